// Round 2
// baseline (393.124 us; speedup 1.0000x reference)
//
#include <hip/hip_runtime.h>

// TGCNCell forward:
//   h_agg = segment_sum(x[src], dst);  gates = h_agg @ W_ih.T + b_ih + b_hh
//   c = sigm(i)*tanh(g); h = sigm(o)*tanh(c); out = relu(h)
// f-gate and W_hh are numerically unused.
//
// Strategy (R2): the direct per-feature atomic scatter is capped at the
// chip-wide 128 atomics/cycle L2 ceiling (measured 167us for 51.2M atomics).
// Build CSR by dst via counting sort (3.2M atomics total), then fused
// gather+gates kernel with high occupancy.

constexpr int NN = 100000;   // nodes
constexpr int NE = 1600000;  // edges
constexpr int F  = 32;       // feats

// ws layout (int elements):
constexpr int OFS_CNT    = 0;         // [NN]
constexpr int OFS_START  = 102400;    // [NN]
constexpr int OFS_CURSOR = 204800;    // [NN]
constexpr int OFS_SORTED = 307200;    // [NE]
constexpr int OFS_SUMS   = 307200 + NE; // [128]
constexpr int WS_INTS    = OFS_SUMS + 128;

constexpr int NB1 = (NN + 1023) / 1024;   // 98 scan blocks

// ---------------------------------------------------------------------------
// A: histogram of dst
// ---------------------------------------------------------------------------
__global__ __launch_bounds__(256) void k_count(const int* __restrict__ dst,
                                               int* __restrict__ cnt) {
    int e = blockIdx.x * 256 + threadIdx.x;
    if (e < NE) atomicAdd(&cnt[dst[e]], 1);
}

// ---------------------------------------------------------------------------
// B1: per-block (1024-wide) exclusive scan of cnt -> start, block sums -> sums
// ---------------------------------------------------------------------------
__global__ __launch_bounds__(1024) void k_scan1(const int* __restrict__ cnt,
                                                int* __restrict__ start,
                                                int* __restrict__ sums) {
    __shared__ int a[1024], b[1024];
    int t = threadIdx.x;
    int i = blockIdx.x * 1024 + t;
    int v = (i < NN) ? cnt[i] : 0;
    a[t] = v;
    __syncthreads();
    int* pin = a; int* pout = b;
    for (int off = 1; off < 1024; off <<= 1) {
        pout[t] = (t >= off) ? (pin[t] + pin[t - off]) : pin[t];
        __syncthreads();
        int* tmp = pin; pin = pout; pout = tmp;
    }
    if (i < NN) start[i] = pin[t] - v;        // exclusive
    if (t == 1023) sums[blockIdx.x] = pin[1023];
}

// ---------------------------------------------------------------------------
// B2: exclusive scan of the NB1 block sums (single block)
// ---------------------------------------------------------------------------
__global__ __launch_bounds__(128) void k_scan2(int* __restrict__ sums) {
    __shared__ int ls[128];
    int t = threadIdx.x;
    ls[t] = (t < NB1) ? sums[t] : 0;
    __syncthreads();
    if (t == 0) {
        int acc = 0;
        for (int k = 0; k < NB1; ++k) { int c = ls[k]; ls[k] = acc; acc += c; }
    }
    __syncthreads();
    if (t < NB1) sums[t] = ls[t];
}

// ---------------------------------------------------------------------------
// B3: start[i] += sums[i/1024]; cursor[i] = start[i]
// ---------------------------------------------------------------------------
__global__ __launch_bounds__(256) void k_scanadd(int* __restrict__ start,
                                                 int* __restrict__ cursor,
                                                 const int* __restrict__ sums) {
    int i = blockIdx.x * 256 + threadIdx.x;
    if (i < NN) {
        int s = start[i] + sums[i >> 10];
        start[i] = s;
        cursor[i] = s;
    }
}

// ---------------------------------------------------------------------------
// C: bucket-scatter src by dst -> sorted
// ---------------------------------------------------------------------------
__global__ __launch_bounds__(256) void k_bucket(const int* __restrict__ src,
                                                const int* __restrict__ dst,
                                                int* __restrict__ cursor,
                                                int* __restrict__ sorted) {
    int e = blockIdx.x * 256 + threadIdx.x;
    if (e < NE) {
        int d = dst[e];
        int pos = atomicAdd(&cursor[d], 1);
        sorted[pos] = src[e];
    }
}

// ---------------------------------------------------------------------------
// D: fused gather + gates.  Block of 256 handles groups of 8 nodes
// (grid-stride).  Gather: half-wave (32 lanes = feature dim) per node,
// edge ids loaded coalesced then shfl-broadcast; x-row reads are 128B
// contiguous per half-wave.  Gates: thread = (node, j), W staged in LDS
// with stride 33 (conflict-free).
// ---------------------------------------------------------------------------
__device__ __forceinline__ float sigm(float v)   { return 1.0f / (1.0f + __expf(-v)); }
__device__ __forceinline__ float tanhf_(float v) { return 1.0f - 2.0f / (__expf(2.0f * v) + 1.0f); }

constexpr int GROUPS = (NN + 7) / 8;   // 12500

__global__ __launch_bounds__(256) void k_gather_gates(
    const float* __restrict__ x,
    const int*   __restrict__ cnt,
    const int*   __restrict__ start,
    const int*   __restrict__ sorted,
    const float* __restrict__ W,       // (128,32) row-major
    const float* __restrict__ b_ih,
    const float* __restrict__ b_hh,
    float*       __restrict__ out)
{
    __shared__ float Ws[96 * 33];      // rows: 0-31 = i, 32-63 = g, 64-95 = o
    __shared__ float bs[96];
    __shared__ float hs[8][32];

    const int t = threadIdx.x;

    for (int idx = t; idx < 96 * 32; idx += 256) {
        int r = idx >> 5, k = idx & 31;
        int srcRow = (r < 32) ? r : r + 32;      // skip f rows 32..63
        Ws[r * 33 + k] = W[srcRow * 32 + k];
    }
    if (t < 96) {
        int srcRow = (t < 32) ? t : t + 32;
        bs[t] = b_ih[srcRow] + b_hh[srcRow];
    }
    __syncthreads();

    const int lane = t & 31;    // feature (gather) / output col j (gates)
    const int nl   = t >> 5;    // node-in-group

    for (int g = blockIdx.x; g < GROUPS; g += gridDim.x) {
        // ---- gather phase: 32 lanes per node ----
        int d = g * 8 + nl;
        float v = 0.0f;
        if (d < NN) {
            int deg = cnt[d];
            int st  = start[d];
            for (int base = 0; base < deg; base += 32) {
                int m = deg - base; if (m > 32) m = 32;
                int sv = (lane < m) ? sorted[st + base + lane] : 0;
                for (int e = 0; e < m; ++e) {
                    int s = __shfl(sv, e, 32);
                    v += x[s * F + lane];
                }
            }
        }
        hs[nl][lane] = v;
        __syncthreads();

        // ---- gates phase: thread = (node nl, col j=lane) ----
        if (d < NN) {
            const float* h  = hs[nl];
            const float* wi = &Ws[lane * 33];
            const float* wg = &Ws[(32 + lane) * 33];
            const float* wo = &Ws[(64 + lane) * 33];
            float ai = bs[lane], ag = bs[32 + lane], ao = bs[64 + lane];
            #pragma unroll
            for (int k = 0; k < 32; ++k) {
                float hv = h[k];
                ai += hv * wi[k];
                ag += hv * wg[k];
                ao += hv * wo[k];
            }
            float c  = sigm(ai) * tanhf_(ag);
            float hh = sigm(ao) * tanhf_(c);
            out[d * F + lane] = fmaxf(hh, 0.0f);
        }
        __syncthreads();   // hs reused next group
    }
}

// ---------------------------------------------------------------------------
extern "C" void kernel_launch(void* const* d_in, const int* in_sizes, int n_in,
                              void* d_out, int out_size, void* d_ws, size_t ws_size,
                              hipStream_t stream) {
    const float* x    = (const float*)d_in[0];
    const int*   src  = (const int*)  d_in[1];
    const int*   dst  = (const int*)  d_in[2];
    const float* W_ih = (const float*)d_in[3];
    // d_in[4] = W_hh : unused numerically
    const float* b_ih = (const float*)d_in[5];
    const float* b_hh = (const float*)d_in[6];
    float* out = (float*)d_out;

    int* w      = (int*)d_ws;
    int* cnt    = w + OFS_CNT;
    int* start  = w + OFS_START;
    int* cursor = w + OFS_CURSOR;
    int* sorted = w + OFS_SORTED;
    int* sums   = w + OFS_SUMS;

    hipMemsetAsync(cnt, 0, NN * sizeof(int), stream);

    k_count  <<<(NE + 255) / 256, 256, 0, stream>>>(dst, cnt);
    k_scan1  <<<NB1, 1024, 0, stream>>>(cnt, start, sums);
    k_scan2  <<<1, 128, 0, stream>>>(sums);
    k_scanadd<<<(NN + 255) / 256, 256, 0, stream>>>(start, cursor, sums);
    k_bucket <<<(NE + 255) / 256, 256, 0, stream>>>(src, dst, cursor, sorted);
    k_gather_gates<<<2048, 256, 0, stream>>>(x, cnt, start, sorted,
                                             W_ih, b_ih, b_hh, out);
}

// Round 5
// 385.579 us; speedup vs baseline: 1.0196x; 1.0196x over previous
//
#include <hip/hip_runtime.h>

// TGCNCell forward:
//   h_agg = segment_sum(x[src], dst);  gates = h_agg @ W_ih.T + b_ih + b_hh
//   c = sigm(i)*tanh(g); h = sigm(o)*tanh(c); out = relu(h)
// f-gate rows (32:64) and W_hh are numerically unused.
//
// R5: R3 design with the pass-1 trip-count bug fixed (EPB=3200 is NOT a
// multiple of 256; the unrolled `i < EPB/256` loops dropped 128 edges/block).
// Coarse 500-bin counting sort (200 nodes/bin, packed u32 edges, coalesced
// segment writes), then one block per bin accumulates h_agg in LDS
// (ds_add_f32, no global atomics) and computes gates fused. h_agg never
// touches global memory.

constexpr int NN   = 100000;
constexpr int NE   = 1600000;
constexpr int F    = 32;
constexpr int NBIN = 500;          // bins; NBIN*NPB == NN exactly
constexpr int NPB  = 200;          // nodes per bin  (dstLocal fits 8 bits)
constexpr int CAP  = 4096;         // segment capacity (Poisson max ~3390, 16 sigma)
constexpr int EPB  = NE / NBIN;    // 3200 edges per pass-1 block (exact)
static_assert(NBIN * NPB == NN, "bin geometry");
static_assert(NBIN * EPB == NE, "edge partition");

// ---------------------------------------------------------------------------
// Pass 1: coarse counting sort of edges by dst-bin.
// Per block: LDS histogram -> scan -> global space reservation -> LDS-staged
// scatter -> coalesced-run global writes of packed (src<<8 | dstLocal).
// ---------------------------------------------------------------------------
__global__ __launch_bounds__(256) void p1_bin(
    const int* __restrict__ src,
    const int* __restrict__ dst,
    unsigned int* __restrict__ seg,     // [NBIN*CAP]
    int* __restrict__ fill)             // [NBIN], zeroed before launch
{
    __shared__ int hist[512];
    __shared__ int sbase[512];          // exclusive scan of hist (block-local)
    __shared__ int cur[512];            // block-local cursors
    __shared__ int adj[512];            // global_segment_pos = adj[bin] + local_pos
    __shared__ int ps[256], ps2[256];
    __shared__ unsigned int stg[EPB];   // staged packed edges, bin-sorted (12.8KB)
    __shared__ int gpos[EPB];           // staged global positions        (12.8KB)

    const int t  = threadIdx.x;
    const int e0 = blockIdx.x * EPB;

    hist[t] = 0; hist[t + 256] = 0;
    __syncthreads();

    // EPB (3200) is NOT a multiple of 256 -> generic strided loop
    for (int e = e0 + t; e < e0 + EPB; e += 256) {
        unsigned d = (unsigned)dst[e];
        atomicAdd(&hist[d / NPB], 1);
    }
    __syncthreads();

    // exclusive scan of hist[0..511] (pairs + Hillis-Steele over 256 sums)
    int a = hist[2 * t], b = hist[2 * t + 1];
    ps[t] = a + b;
    __syncthreads();
    int* pin = ps; int* pout = ps2;
    for (int off = 1; off < 256; off <<= 1) {
        pout[t] = (t >= off) ? (pin[t] + pin[t - off]) : pin[t];
        __syncthreads();
        int* tmp = pin; pin = pout; pout = tmp;
    }
    int exclPair = pin[t] - (a + b);
    sbase[2 * t]     = exclPair;
    sbase[2 * t + 1] = exclPair + a;
    __syncthreads();

    // reserve space in each bin's global segment
    for (int bb = t; bb < NBIN; bb += 256) {
        int c  = hist[bb];
        int gb = (c > 0) ? atomicAdd(&fill[bb], c) : 0;
        adj[bb] = bb * CAP + gb - sbase[bb];
        cur[bb] = sbase[bb];
    }
    __syncthreads();

    // scatter into LDS staging (sorted by bin), remember global positions
    for (int e = e0 + t; e < e0 + EPB; e += 256) {
        unsigned d = (unsigned)dst[e];
        unsigned s = (unsigned)src[e];
        unsigned bin = d / NPB;
        unsigned dl  = d - bin * NPB;
        int lp = atomicAdd(&cur[bin], 1);          // block-local sorted position
        stg[lp]  = (s << 8) | dl;
        gpos[lp] = adj[bin] + lp;
    }
    __syncthreads();

    // coalesced-run writeout: consecutive lp within a bin-chunk -> consecutive addrs
    for (int p = t; p < EPB; p += 256) {
        seg[gpos[p]] = stg[p];
    }
}

// ---------------------------------------------------------------------------
// Pass 2: one block per bin. Accumulate h_agg for 200 nodes in LDS via
// ds_add_f32, then fused gates + activations, write out directly.
// ---------------------------------------------------------------------------
__device__ __forceinline__ float sigm(float v)  { return 1.0f / (1.0f + __expf(-v)); }
__device__ __forceinline__ float tanh_(float v) { return 1.0f - 2.0f / (__expf(2.0f * v) + 1.0f); }

__global__ __launch_bounds__(512) void p2_agg_gates(
    const float* __restrict__ x,
    const unsigned int* __restrict__ seg,
    const int* __restrict__ fill,
    const float* __restrict__ W,        // (128,32) row-major
    const float* __restrict__ b_ih,
    const float* __restrict__ b_hh,
    float* __restrict__ out)
{
    __shared__ float hs[NPB * F];       // 200x32 = 25.6KB
    __shared__ float Ws[96 * 33];       // i,g,o rows, stride 33 (conflict-free)
    __shared__ float bs[96];

    const int t   = threadIdx.x;
    const int bin = blockIdx.x;

    for (int i = t; i < 96 * 32; i += 512) {
        int r = i >> 5, k = i & 31;
        int sr = (r < 32) ? r : r + 32;           // skip f rows 32..63
        Ws[r * 33 + k] = W[sr * 32 + k];
    }
    if (t < 96) { int sr = (t < 32) ? t : t + 32; bs[t] = b_ih[sr] + b_hh[sr]; }
    for (int i = t; i < NPB * F; i += 512) hs[i] = 0.0f;
    __syncthreads();

    // gather: 16 groups of 32 lanes; group = one edge, lane = feature
    const int lane = t & 31, g = t >> 5;
    int nE = fill[bin]; if (nE > CAP) nE = CAP;
    const unsigned int* segb = seg + bin * CAP;
    for (int base = 0; base < nE; base += 16) {
        int e = base + g;
        if (e < nE) {
            unsigned v = segb[e];                  // broadcast within group
            int s  = (int)(v >> 8);
            int dl = (int)(v & 255u);
            atomicAdd(&hs[dl * F + lane], x[s * F + lane]);   // ds_add_f32
        }
    }
    __syncthreads();

    // gates: thread -> (node, col j); hs row broadcast, Ws stride-33 banks
    for (int i = t; i < NPB * F; i += 512) {
        int node = i >> 5, j = i & 31;
        int n = bin * NPB + node;                  // < NN always (500*200 == NN)
        const float* h  = &hs[node * F];
        const float* wi = &Ws[j * 33];
        const float* wg = &Ws[(32 + j) * 33];
        const float* wo = &Ws[(64 + j) * 33];
        float ai = bs[j], ag = bs[32 + j], ao = bs[64 + j];
        #pragma unroll
        for (int k = 0; k < F; ++k) {
            float hv = h[k];
            ai += hv * wi[k];
            ag += hv * wg[k];
            ao += hv * wo[k];
        }
        float c  = sigm(ai) * tanh_(ag);
        float hh = sigm(ao) * tanh_(c);
        out[n * F + j] = fmaxf(hh, 0.0f);
    }
}

// ---------------------------------------------------------------------------
extern "C" void kernel_launch(void* const* d_in, const int* in_sizes, int n_in,
                              void* d_out, int out_size, void* d_ws, size_t ws_size,
                              hipStream_t stream) {
    const float* x    = (const float*)d_in[0];
    const int*   src  = (const int*)  d_in[1];
    const int*   dst  = (const int*)  d_in[2];
    const float* W_ih = (const float*)d_in[3];
    // d_in[4] = W_hh : numerically unused
    const float* b_ih = (const float*)d_in[5];
    const float* b_hh = (const float*)d_in[6];
    float* out = (float*)d_out;

    unsigned int* seg = (unsigned int*)d_ws;            // NBIN*CAP u32 = 8.2MB
    int* fill = (int*)(seg + (size_t)NBIN * CAP);       // NBIN ints

    hipMemsetAsync(fill, 0, NBIN * sizeof(int), stream);
    p1_bin      <<<NBIN, 256, 0, stream>>>(src, dst, seg, fill);
    p2_agg_gates<<<NBIN, 512, 0, stream>>>(x, seg, fill, W_ih, b_ih, b_hh, out);
}